// Round 11
// baseline (254.447 us; speedup 1.0000x reference)
//
#include <hip/hip_runtime.h>
#include <hip/hip_bf16.h>
#include <math.h>
#include <stdint.h>

using bf16 = __hip_bfloat16;
typedef __attribute__((ext_vector_type(8))) short short8;
typedef __attribute__((ext_vector_type(4))) short short4v;
typedef __attribute__((ext_vector_type(4))) float float4v;

#define MFMA16(a, b, c) __builtin_amdgcn_mfma_f32_16x16x32_bf16(a, b, c, 0, 0, 0)

__device__ __forceinline__ short bfbits(float f) {
  bf16 h = (bf16)f;
  return *(short*)&h;
}

__device__ __forceinline__ short8 ld_cvt8(const float* p) {
  union { float4v v[2]; float f[8]; } u;
  u.v[0] = *(const float4v*)p;
  u.v[1] = *(const float4v*)(p + 4);
  short8 r;
#pragma unroll
  for (int j = 0; j < 8; j++) r[j] = bfbits(u.f[j]);
  return r;
}

// global -> LDS direct copy, 16B per lane. LDS dest = uniform base + lane*16.
__device__ __forceinline__ void gload16(const bf16* g, bf16* l) {
  __builtin_amdgcn_global_load_lds(
      (const __attribute__((address_space(1))) void*)g,
      (__attribute__((address_space(3))) void*)l, 16, 0, 0);
}

// ---------------------------------------------------------------------------
// One-shot fp32 -> bf16 conversion of x and the 4 weights.
// ---------------------------------------------------------------------------
__global__ __launch_bounds__(256) void conv_all(
    const float* __restrict__ x, const float* __restrict__ w0,
    const float* __restrict__ w1, const float* __restrict__ w2,
    const float* __restrict__ w3, bf16* __restrict__ cx,
    bf16* __restrict__ cw) {
  size_t gid = ((size_t)blockIdx.x * 256 + threadIdx.x) * 8;
  const float* src;
  bf16* dst;
  size_t off;
  if (gid < 4194304) {
    src = x; dst = cx; off = gid;
  } else {
    size_t r = gid - 4194304;
    int wi = (int)(r >> 18);
    src = wi == 0 ? w0 : wi == 1 ? w1 : wi == 2 ? w2 : w3;
    dst = cw + ((size_t)wi << 18);
    off = r & 262143;
  }
  *(short8*)(dst + off) = ld_cvt8(src + off);
}

// ---------------------------------------------------------------------------
// GEMM (NT, all-bf16): software-pipelined, dbuf LDS, gload_lds width=16,
// both-sides XOR swizzle, BK=64, one barrier per k-step.
// MODE 0: out[b,h,t,d] bf16 scaled (Q,K). MODE 1: out[m,n] fp32 (proj).
// MODE 2: out[b,h,d,t'] bf16 (V^T) with the PV slot-permutation baked into
//         t' = (t & ~63) | M(t&63), M(k) = (k&32)|((k&12)<<1)|((k&16)>>2)|(k&3)
//         so attn can DMA-stage V and read straight swizzled b128 frags.
// ---------------------------------------------------------------------------
template <int MODE, int MT>
__device__ __forceinline__ void gemm_body(bf16* As, bf16* Bs,
                                          const bf16* __restrict__ A,
                                          const bf16* __restrict__ W,
                                          void* __restrict__ outp,
                                          float oscale) {
  constexpr int MI = MT / 32;
  constexpr int ASZ = MT * 64;
  constexpr int BSZ = 128 * 64;
  const int bm = blockIdx.x * MT, bn = blockIdx.y * 128;
  const int tid = threadIdx.x;
  const int lane = tid & 63;
  const int wave = tid >> 6;
  const int lr = lane & 15, quad = lane >> 4;
  const int wm = (wave & 1) * (MT / 2), wn = (wave >> 1) * 64;

  const int srow = lane >> 3;
  const int scl = (lane & 7) ^ (srow & 7);
  const int rsw = lr & 7;

  float4v acc[MI][4] = {};

  auto stage = [&](int k0, int b) {
    bf16* Ad = As + b * ASZ;
    bf16* Bd = Bs + b * BSZ;
#pragma unroll
    for (int j = 0; j < MT / 32; j++) {
      const int m = wave + 4 * j;
      gload16(&A[(size_t)(bm + 8 * m + srow) * 512 + k0 + scl * 8],
              &Ad[(8 * m) * 64]);
    }
#pragma unroll
    for (int j = 0; j < 4; j++) {
      const int m = wave + 4 * j;
      gload16(&W[(size_t)(bn + 8 * m + srow) * 512 + k0 + scl * 8],
              &Bd[(8 * m) * 64]);
    }
  };

  stage(0, 0);
  __syncthreads();  // buf0 staged (one-time pipeline fill)

  for (int s = 0; s < 8; s++) {
    if (s + 1 < 8) stage(64 * (s + 1), (s + 1) & 1);  // overlaps compute
    const bf16* Ac = As + (s & 1) * ASZ;
    const bf16* Bc = Bs + (s & 1) * BSZ;
#pragma unroll
    for (int kk = 0; kk < 2; kk++) {
      short8 af[MI], bfv[4];
#pragma unroll
      for (int i = 0; i < MI; i++)
        af[i] = *(const short8*)
            &Ac[(wm + i * 16 + lr) * 64 + ((4 * kk + quad) ^ rsw) * 8];
#pragma unroll
      for (int i = 0; i < 4; i++)
        bfv[i] = *(const short8*)
            &Bc[(wn + i * 16 + lr) * 64 + ((4 * kk + quad) ^ rsw) * 8];
#pragma unroll
      for (int mi = 0; mi < MI; mi++)
#pragma unroll
        for (int ni = 0; ni < 4; ni++)
          acc[mi][ni] = MFMA16(af[mi], bfv[ni], acc[mi][ni]);
    }
    __syncthreads();
  }

  const int row0 = bm + wm + quad * 4;
  const int col0 = bn + wn + lr;
#pragma unroll
  for (int mi = 0; mi < MI; mi++) {
#pragma unroll
    for (int ni = 0; ni < 4; ni++) {
      const int col = col0 + ni * 16;
      if (MODE == 1) {
        float* out = (float*)outp;
#pragma unroll
        for (int i = 0; i < 4; i++) {
          int m = row0 + mi * 16 + i;
          out[(size_t)m * 512 + col] = acc[mi][ni][i];
        }
      } else if (MODE == 0) {
        bf16* out = (bf16*)outp;
        const int hh = col >> 6, d = col & 63;
#pragma unroll
        for (int i = 0; i < 4; i++) {
          int m = row0 + mi * 16 + i;
          int bb = m >> 12, t = m & 4095;
          out[(((size_t)(bb * 8 + hh) * 4096 + t) << 6) + d] =
              (bf16)(acc[mi][ni][i] * oscale);
        }
      } else {
        bf16* out = (bf16*)outp;
        const int hh = col >> 6, d = col & 63;
        int m0 = row0 + mi * 16;
        int bb = m0 >> 12, t0 = m0 & 4095;
        // PV slot-permutation on the within-tile t index (runs of 4 kept)
        int u = t0 & 63;
        int up = (u & 32) | ((u & 12) << 1) | ((u & 16) >> 2) | (u & 3);
        short4v pk;
#pragma unroll
        for (int i = 0; i < 4; i++) pk[i] = bfbits(acc[mi][ni][i]);
        *(short4v*)&out[(((size_t)(bb * 8 + hh) * 64 + d) << 12) +
                        (t0 & ~63) + up] = pk;
      }
    }
  }
}

// 0.125 * log2(e): folded into Q so attention scores are in exp2 domain.
#define QSCALE 0.18033688f

__global__ __launch_bounds__(256) void qkv_kernel(
    const bf16* __restrict__ cx, const bf16* __restrict__ cW,
    bf16* q, bf16* k, bf16* vt) {
  __shared__ __align__(16) bf16 As[2 * 128 * 64];
  __shared__ __align__(16) bf16 Bs[2 * 128 * 64];
  if (blockIdx.z == 0)      gemm_body<0, 128>(As, Bs, cx, cW, q, QSCALE);
  else if (blockIdx.z == 1) gemm_body<0, 128>(As, Bs, cx, cW + 262144, k, 1.0f);
  else                      gemm_body<2, 128>(As, Bs, cx, cW + 2 * 262144, vt, 1.0f);
}

__global__ __launch_bounds__(256) void proj_kernel(
    const bf16* __restrict__ y, const bf16* __restrict__ cWout,
    float* __restrict__ out) {
  __shared__ __align__(16) bf16 As[2 * 64 * 64];
  __shared__ __align__(16) bf16 Bs[2 * 128 * 64];
  gemm_body<1, 64>(As, Bs, y, cWout, out, 1.0f);
}

// ---------------------------------------------------------------------------
// Flash attention (causal), max-free exp2 softmax, in-register P, split-K 2
// groups, diagonal pairing (uniform 33/32 steps), ones-MFMA l.
// This revision: HALVE LDS TRAFFIC.
//  - K fragments load GLOBAL->REG directly (per-lane 16B, L1-serves the 4-way
//    wave duplication); loads for step s+1 issue right after step s's QK
//    consumes kf (single register set, ~500cyc cover). K never touches LDS.
//  - V staged via global_load_lds (2 instr/wave) from vt that qkv wrote
//    PRE-PERMUTED (slot-perm in t) with pre-swizzled source chunk ->
//    PV B-frags are straight swizzled ds_read_b128. No reg-staging/vstore.
//  - LDS 64KB -> 32.5KB; LDS reads/wave-step 16 -> 8.
// ---------------------------------------------------------------------------
__device__ __forceinline__ int lsw(int row, int col) {
  return (row << 6) + (col ^ ((row & 7) << 3));
}

__device__ __forceinline__ void kload(const bf16* __restrict__ Kh, int kt,
                                      int lr, int quad, short8 (&kf)[4][2]) {
#pragma unroll
  for (int nc = 0; nc < 4; nc++) {
    const bf16* r = Kh + (size_t)(kt * 64 + nc * 16 + lr) * 64 + quad * 8;
    kf[nc][0] = *(const short8*)r;
    kf[nc][1] = *(const short8*)(r + 32);
  }
}

__device__ __forceinline__ void vload_lds(const bf16* __restrict__ Vth, int kt,
                                          int wave, int srow, int scl,
                                          bf16* Vb) {
#pragma unroll
  for (int j = 0; j < 2; j++) {
    const int rb = wave * 16 + 8 * j;
    gload16(&Vth[(size_t)(rb + srow) * 4096 + kt * 64 + scl * 8],
            &Vb[rb * 64]);
  }
}

__device__ __forceinline__ void qk_phase(const short8 (&kf)[4][2], short8 qf0,
                                         short8 qf1, float4v (&S)[4]) {
  __builtin_amdgcn_s_setprio(1);
#pragma unroll
  for (int nc = 0; nc < 4; nc++) {
    S[nc] = MFMA16(kf[nc][0], qf0, S[nc]);
    S[nc] = MFMA16(kf[nc][1], qf1, S[nc]);
  }
  __builtin_amdgcn_s_setprio(0);
}

template <bool DIAG>
__device__ __forceinline__ void sp_phase(const float4v (&S)[4],
                                         const bf16* __restrict__ Vc,
                                         short8 ones, int wave, int lr,
                                         int quad, float4v& Lacc, float4v* O) {
  // softmax (exp2 domain) + in-lane P pack (P[q=lr][k'=16nc+4quad+i]).
  short8 pf0, pf1;
#pragma unroll
  for (int nc = 0; nc < 4; nc++) {
#pragma unroll
    for (int i = 0; i < 4; i++) {
      float pv = exp2f(S[nc][i]);
      if (DIAG) {
        int kl = nc * 16 + quad * 4 + i;
        pv = (kl > wave * 16 + lr) ? 0.f : pv;
      }
      short bb = bfbits(pv);
      if (nc == 0)      pf0[i] = bb;
      else if (nc == 1) pf0[4 + i] = bb;
      else if (nc == 2) pf1[i] = bb;
      else              pf1[4 + i] = bb;
    }
  }

  __builtin_amdgcn_s_setprio(1);
  // l row-sums on the MFMA pipe: Lacc[i] = l[q = wave*16 + quad*4 + i].
  Lacc = MFMA16(pf0, ones, Lacc);
  Lacc = MFMA16(pf1, ones, Lacc);

  // PV: V pre-permuted -> straight swizzled b128 reads.
#pragma unroll
  for (int nc = 0; nc < 4; nc++) {
    const int row = nc * 16 + lr;
    short8 vfa = *(const short8*)&Vc[lsw(row, quad * 8)];
    short8 vfb = *(const short8*)&Vc[lsw(row, 32 + quad * 8)];
    O[nc] = MFMA16(pf0, vfa, O[nc]);
    O[nc] = MFMA16(pf1, vfb, O[nc]);
  }
  __builtin_amdgcn_s_setprio(0);
}

__global__ __launch_bounds__(512, 4) void attn_kernel(const bf16* __restrict__ Qg,
                                                      const bf16* __restrict__ Kg,
                                                      const bf16* __restrict__ Vtg,
                                                      bf16* __restrict__ Y) {
  constexpr int T = 4096;
  __shared__ __align__(16) bf16 Vs[2][2][64 * 64];  // [group][dbuf] = 32 KB
  __shared__ __align__(16) float Lx[2][64];

  const int bx = blockIdx.x;           // 0..511
  const int p = bx >> 4;               // pair index: q-tiles p and 63-p
  const int pB = 63 - p;
  const int hb = bx & 15;
  const int h = hb >> 1, b = hb & 1;
  const size_t ho = ((size_t)(b * 8 + h)) * T * 64;
  const bf16* Qh = Qg + ho;
  const bf16* Kh = Kg + ho;
  const bf16* Vth = Vtg + ho;

  const int tid = threadIdx.x;
  const int G = tid >> 8;              // split-K group (4 waves each)
  const int t = tid & 255;
  const int wave = t >> 6, lane = t & 63;
  const int lr = lane & 15, quad = lane >> 4;

  // uniform split of the pair's 65 kt-tiles (33 G0 / 32 G1)
  const int hA = (p + 2) >> 1;
  const int hB = (65 - p) >> 1;
  const int myA = G ? (p + 1 - hA) : hA;
  const int aB = G ? hA : 0;
  const int bB = G ? hB : 0;
  const int mysteps = myA + (G ? (64 - p - hB) : hB);
  auto kt_of = [&](int s) { return (s < myA) ? (aB + s) : (bB + (s - myA)); };

  const int srowV = lane >> 3;
  const int sclV = (lane & 7) ^ (srowV & 7);

  const int kt0 = kt_of(0);

  // K(0) frags -> regs; V(0) -> LDS via DMA (issued before Q staging)
  short8 kf[4][2];
  kload(Kh, kt0, lr, quad, kf);
  vload_lds(Vth, kt0, wave, srowV, sclV, Vs[G][0]);

  // Q staging into both groups' dbuf-1 regions (read by all waves)
  {
    int rr = tid >> 3, c = (tid & 7) * 8;
    *(short8*)&Vs[0][1][lsw(rr, c)] =
        *(const short8*)&Qh[(size_t)(p * 64 + rr) * 64 + c];
    *(short8*)&Vs[1][1][lsw(rr, c)] =
        *(const short8*)&Qh[(size_t)(pB * 64 + rr) * 64 + c];
  }
  __syncthreads();  // V(0) DMA drained + Q visible
  short8 qfA0 = *(const short8*)&Vs[0][1][lsw(wave * 16 + lr, quad * 8)];
  short8 qfA1 = *(const short8*)&Vs[0][1][lsw(wave * 16 + lr, 32 + quad * 8)];
  short8 qfB0 = *(const short8*)&Vs[1][1][lsw(wave * 16 + lr, quad * 8)];
  short8 qfB1 = *(const short8*)&Vs[1][1][lsw(wave * 16 + lr, 32 + quad * 8)];
  __syncthreads();  // all qf reads done before step-0's V(1) DMA hits dbuf-1

  short8 ones;
#pragma unroll
  for (int j = 0; j < 8; j++) ones[j] = (short)0x3F80;  // bf16 1.0

  float4v OA[4] = {}, OB[4] = {};
  float4v LA = {}, LB = {};

  for (int s = 0; s < 33; s++) {       // uniform barrier count (G1 idles #32)
    if (s + 1 < mysteps)
      vload_lds(Vth, kt_of(s + 1), wave, srowV, sclV, Vs[G][(s + 1) & 1]);
    if (s < mysteps) {
      const bool isA = s < myA;
      float4v S[4] = {};
      qk_phase(kf, isA ? qfA0 : qfB0, isA ? qfA1 : qfB1, S);
      if (s + 1 < mysteps) kload(Kh, kt_of(s + 1), lr, quad, kf);  // after use
      const bf16* Vc = Vs[G][s & 1];
      const int kt = kt_of(s);
      if (isA) {
        if (kt == p) sp_phase<true>(S, Vc, ones, wave, lr, quad, LA, OA);
        else         sp_phase<false>(S, Vc, ones, wave, lr, quad, LA, OA);
      } else {
        if (kt == pB) sp_phase<true>(S, Vc, ones, wave, lr, quad, LB, OB);
        else          sp_phase<false>(S, Vc, ones, wave, lr, quad, LB, OB);
      }
    }
    __syncthreads();  // V(s+1) DMA drained; all readers of Vs[G][s&1] done
  }

  // ---- split-k combine: G1 dumps partials into LDS, G0 combines ----------
  float* OpA = (float*)&Vs[0][0][0];   // 16 KB (spans Vs[0][0..1])
  float* OpB = (float*)&Vs[1][0][0];   // 16 KB (spans Vs[1][0..1])
  float* LpA = Lx[0];
  float* LpB = Lx[1];
  const int r0 = wave * 16 + quad * 4;
  if (G == 1) {
#pragma unroll
    for (int nc = 0; nc < 4; nc++)
#pragma unroll
      for (int i = 0; i < 4; i++) {
        OpA[(r0 + i) * 64 + nc * 16 + lr] = OA[nc][i];
        OpB[(r0 + i) * 64 + nc * 16 + lr] = OB[nc][i];
      }
    if (lr == 0) {
#pragma unroll
      for (int i = 0; i < 4; i++) { LpA[r0 + i] = LA[i]; LpB[r0 + i] = LB[i]; }
    }
  }
  __syncthreads();
  if (G == 0) {
    float invA[4], invB[4];
#pragma unroll
    for (int i = 0; i < 4; i++) {
      invA[i] = 1.f / (LA[i] + LpA[r0 + i]);
      invB[i] = 1.f / (LB[i] + LpB[r0 + i]);
    }
    const size_t ybA = ((size_t)b * T + p * 64 + r0) * 512 + h * 64;
    const size_t ybB = ((size_t)b * T + pB * 64 + r0) * 512 + h * 64;
#pragma unroll
    for (int nc = 0; nc < 4; nc++)
#pragma unroll
      for (int i = 0; i < 4; i++) {
        float oa = OA[nc][i] + OpA[(r0 + i) * 64 + nc * 16 + lr];
        float ob = OB[nc][i] + OpB[(r0 + i) * 64 + nc * 16 + lr];
        Y[ybA + (size_t)i * 512 + nc * 16 + lr] = (bf16)(oa * invA[i]);
        Y[ybB + (size_t)i * 512 + nc * 16 + lr] = (bf16)(ob * invB[i]);
      }
  }
}

// ---------------------------------------------------------------------------
extern "C" void kernel_launch(void* const* d_in, const int* in_sizes, int n_in,
                              void* d_out, int out_size, void* d_ws, size_t ws_size,
                              hipStream_t stream) {
  (void)out_size; (void)ws_size;
  // Interface verified R9: dict-order slots, fp32 in, x=[B,T,C], fp32 out.
  const int NX = 8192 * 512;
  int xi = 0;
  for (int i = 0; i < n_in; i++)
    if (in_sizes[i] == NX) { xi = i; break; }
  const float* x = (const float*)d_in[xi];
  const float* wsrc[4];
  int wn = 0;
  for (int i = 0; i < n_in && wn < 4; i++)
    if (i != xi) wsrc[wn++] = (const float*)d_in[i];

  bf16* ws = (bf16*)d_ws;
  const size_t HE = (size_t)NX;
  bf16* q  = ws;                 // 8 MB
  bf16* k  = q + HE;             // 8 MB
  bf16* yx = k + HE;             // 8 MB: bf16 x during qkv, y after attn
  bf16* cw = yx + HE;            // 2 MB (4 weights)  -> 26 MB ws total
  bf16* vt = (bf16*)d_out;       // V^T staged in d_out, consumed before proj
  float* out = (float*)d_out;

  conv_all<<<2560, 256, 0, stream>>>(x, wsrc[0], wsrc[1], wsrc[2], wsrc[3],
                                     yx, cw);
  qkv_kernel<<<dim3(64, 4, 3), 256, 0, stream>>>(yx, cw, q, k, vt);
  attn_kernel<<<512, 512, 0, stream>>>(q, k, vt, yx);
  proj_kernel<<<dim3(128, 4), 256, 0, stream>>>(yx, cw + 3 * 262144, out);
}

// Round 12
// 177.012 us; speedup vs baseline: 1.4375x; 1.4375x over previous
//
#include <hip/hip_runtime.h>
#include <hip/hip_bf16.h>
#include <math.h>
#include <stdint.h>

using bf16 = __hip_bfloat16;
typedef __attribute__((ext_vector_type(8))) short short8;
typedef __attribute__((ext_vector_type(4))) short short4v;
typedef __attribute__((ext_vector_type(4))) float float4v;
typedef __attribute__((ext_vector_type(16))) float f32x16;

#define MFMA16(a, b, c) __builtin_amdgcn_mfma_f32_16x16x32_bf16(a, b, c, 0, 0, 0)
#define MFMA32(a, b, c) __builtin_amdgcn_mfma_f32_32x32x16_bf16(a, b, c, 0, 0, 0)

__device__ __forceinline__ short bfbits(float f) {
  bf16 h = (bf16)f;
  return *(short*)&h;
}

__device__ __forceinline__ short8 ld_cvt8(const float* p) {
  union { float4v v[2]; float f[8]; } u;
  u.v[0] = *(const float4v*)p;
  u.v[1] = *(const float4v*)(p + 4);
  short8 r;
#pragma unroll
  for (int j = 0; j < 8; j++) r[j] = bfbits(u.f[j]);
  return r;
}

// global -> LDS direct copy, 16B per lane. LDS dest = uniform base + lane*16.
__device__ __forceinline__ void gload16(const bf16* g, bf16* l) {
  __builtin_amdgcn_global_load_lds(
      (const __attribute__((address_space(1))) void*)g,
      (__attribute__((address_space(3))) void*)l, 16, 0, 0);
}

// ---------------------------------------------------------------------------
// One-shot fp32 -> bf16 conversion of x and the 4 weights.
// ---------------------------------------------------------------------------
__global__ __launch_bounds__(256) void conv_all(
    const float* __restrict__ x, const float* __restrict__ w0,
    const float* __restrict__ w1, const float* __restrict__ w2,
    const float* __restrict__ w3, bf16* __restrict__ cx,
    bf16* __restrict__ cw) {
  size_t gid = ((size_t)blockIdx.x * 256 + threadIdx.x) * 8;
  const float* src;
  bf16* dst;
  size_t off;
  if (gid < 4194304) {
    src = x; dst = cx; off = gid;
  } else {
    size_t r = gid - 4194304;
    int wi = (int)(r >> 18);
    src = wi == 0 ? w0 : wi == 1 ? w1 : wi == 2 ? w2 : w3;
    dst = cw + ((size_t)wi << 18);
    off = r & 262143;
  }
  *(short8*)(dst + off) = ld_cvt8(src + off);
}

// ---------------------------------------------------------------------------
// GEMM (NT, all-bf16): software-pipelined, dbuf LDS, gload_lds width=16,
// both-sides XOR swizzle, BK=64, one barrier per k-step.
// MODE 0: out[b,h,t,d] bf16 scaled (Q,K). MODE 1: out[m,n] fp32 (proj).
// MODE 2: out[b,h,d,t'] bf16 (V^T) with t' = bits 2<->3 of (t&63) swapped:
//         attn's 32x32-PV slot permutation baked into the layout, so attn
//         DMA-stages V linearly and reads straight swizzled b128 frags.
// ---------------------------------------------------------------------------
template <int MODE, int MT>
__device__ __forceinline__ void gemm_body(bf16* As, bf16* Bs,
                                          const bf16* __restrict__ A,
                                          const bf16* __restrict__ W,
                                          void* __restrict__ outp,
                                          float oscale) {
  constexpr int MI = MT / 32;
  constexpr int ASZ = MT * 64;
  constexpr int BSZ = 128 * 64;
  const int bm = blockIdx.x * MT, bn = blockIdx.y * 128;
  const int tid = threadIdx.x;
  const int lane = tid & 63;
  const int wave = tid >> 6;
  const int lr = lane & 15, quad = lane >> 4;
  const int wm = (wave & 1) * (MT / 2), wn = (wave >> 1) * 64;

  const int srow = lane >> 3;
  const int scl = (lane & 7) ^ (srow & 7);
  const int rsw = lr & 7;

  float4v acc[MI][4] = {};

  auto stage = [&](int k0, int b) {
    bf16* Ad = As + b * ASZ;
    bf16* Bd = Bs + b * BSZ;
#pragma unroll
    for (int j = 0; j < MT / 32; j++) {
      const int m = wave + 4 * j;
      gload16(&A[(size_t)(bm + 8 * m + srow) * 512 + k0 + scl * 8],
              &Ad[(8 * m) * 64]);
    }
#pragma unroll
    for (int j = 0; j < 4; j++) {
      const int m = wave + 4 * j;
      gload16(&W[(size_t)(bn + 8 * m + srow) * 512 + k0 + scl * 8],
              &Bd[(8 * m) * 64]);
    }
  };

  stage(0, 0);
  __syncthreads();

  for (int s = 0; s < 8; s++) {
    if (s + 1 < 8) stage(64 * (s + 1), (s + 1) & 1);
    const bf16* Ac = As + (s & 1) * ASZ;
    const bf16* Bc = Bs + (s & 1) * BSZ;
#pragma unroll
    for (int kk = 0; kk < 2; kk++) {
      short8 af[MI], bfv[4];
#pragma unroll
      for (int i = 0; i < MI; i++)
        af[i] = *(const short8*)
            &Ac[(wm + i * 16 + lr) * 64 + ((4 * kk + quad) ^ rsw) * 8];
#pragma unroll
      for (int i = 0; i < 4; i++)
        bfv[i] = *(const short8*)
            &Bc[(wn + i * 16 + lr) * 64 + ((4 * kk + quad) ^ rsw) * 8];
#pragma unroll
      for (int mi = 0; mi < MI; mi++)
#pragma unroll
        for (int ni = 0; ni < 4; ni++)
          acc[mi][ni] = MFMA16(af[mi], bfv[ni], acc[mi][ni]);
    }
    __syncthreads();
  }

  const int row0 = bm + wm + quad * 4;
  const int col0 = bn + wn + lr;
#pragma unroll
  for (int mi = 0; mi < MI; mi++) {
#pragma unroll
    for (int ni = 0; ni < 4; ni++) {
      const int col = col0 + ni * 16;
      if (MODE == 1) {
        float* out = (float*)outp;
#pragma unroll
        for (int i = 0; i < 4; i++) {
          int m = row0 + mi * 16 + i;
          out[(size_t)m * 512 + col] = acc[mi][ni][i];
        }
      } else if (MODE == 0) {
        bf16* out = (bf16*)outp;
        const int hh = col >> 6, d = col & 63;
#pragma unroll
        for (int i = 0; i < 4; i++) {
          int m = row0 + mi * 16 + i;
          int bb = m >> 12, t = m & 4095;
          out[(((size_t)(bb * 8 + hh) * 4096 + t) << 6) + d] =
              (bf16)(acc[mi][ni][i] * oscale);
        }
      } else {
        bf16* out = (bf16*)outp;
        const int hh = col >> 6, d = col & 63;
        int m0 = row0 + mi * 16;
        int bb = m0 >> 12, t0 = m0 & 4095;
        // bits 2<->3 swap of within-64 t index (4-runs preserved, aligned)
        int u = t0 & 63;
        int up = (u & ~12) | ((u & 4) << 1) | ((u & 8) >> 1);
        short4v pk;
#pragma unroll
        for (int i = 0; i < 4; i++) pk[i] = bfbits(acc[mi][ni][i]);
        *(short4v*)&out[(((size_t)(bb * 8 + hh) * 64 + d) << 12) +
                        (t0 & ~63) + up] = pk;
      }
    }
  }
}

// 0.125 * log2(e): folded into Q so attention scores are in exp2 domain.
#define QSCALE 0.18033688f

__global__ __launch_bounds__(256) void qkv_kernel(
    const bf16* __restrict__ cx, const bf16* __restrict__ cW,
    bf16* q, bf16* k, bf16* vt) {
  __shared__ __align__(16) bf16 As[2 * 128 * 64];
  __shared__ __align__(16) bf16 Bs[2 * 128 * 64];
  if (blockIdx.z == 0)      gemm_body<0, 128>(As, Bs, cx, cW, q, QSCALE);
  else if (blockIdx.z == 1) gemm_body<0, 128>(As, Bs, cx, cW + 262144, k, 1.0f);
  else                      gemm_body<2, 128>(As, Bs, cx, cW + 2 * 262144, vt, 1.0f);
}

__global__ __launch_bounds__(256) void proj_kernel(
    const bf16* __restrict__ y, const bf16* __restrict__ cWout,
    float* __restrict__ out) {
  __shared__ __align__(16) bf16 As[2 * 64 * 64];
  __shared__ __align__(16) bf16 Bs[2 * 128 * 64];
  gemm_body<1, 64>(As, Bs, y, cWout, out, 1.0f);
}

// ---------------------------------------------------------------------------
// Flash attention (causal), 32x32x16 MFMA path: each wave covers 32 q-rows,
// halving LDS fragment traffic per unit of work (the measured bottleneck).
// - A/B frag layout (analogy of the verified 16x16 pattern): row = lane&31,
//   contraction slot = 8*(lane>>5)+e. C/D: col=lane&31,
//   row=(r&3)+8*(r>>2)+4*(lane>>5) (HW-verified mapping).
// - Swapped QK^T keeps q lane-local (col=lane&31); P packed in-register;
//   PV slot permutation absorbed by V's bit2<->3-swapped t layout (MODE 2).
// - 8 waves = 4 streams x 2 q-halves. Tile A (p+1 units) gets nA streams,
//   tile B (64-p) gets 4-nA; streams split their tile's kts (split-K).
//   K/V single-buffered per stream (4 x 16KB = 64KB -> 2 blocks/CU,
//   16 waves/CU), 2 barriers/step, DMA staging (K by qh0 wave, V by qh1).
// - l: scalar adds + shfl_xor(32); partial O/l combined via LDS epilogue.
// ---------------------------------------------------------------------------
__device__ __forceinline__ int lsw(int row, int col) {
  return (row << 6) + (col ^ ((row & 7) << 3));
}

__global__ __launch_bounds__(512, 4) void attn_kernel(const bf16* __restrict__ Qg,
                                                      const bf16* __restrict__ Kg,
                                                      const bf16* __restrict__ Vtg,
                                                      bf16* __restrict__ Y) {
  constexpr int T = 4096;
  __shared__ __align__(16) bf16 KVs[8][64 * 64];  // stream st: K=2st, V=2st+1
  __shared__ float Lsh[8][32];

  const int bx = blockIdx.x;           // 0..511
  const int p = bx >> 4, pB = 63 - p;  // paired q-tiles
  const int hb = bx & 15;
  const int h = hb >> 1, b = hb & 1;
  const size_t ho = ((size_t)(b * 8 + h)) * T * 64;
  const bf16* Qh = Qg + ho;
  const bf16* Kh = Kg + ho;
  const bf16* Vth = Vtg + ho;

  const int tid = threadIdx.x;
  const int w = tid >> 6, lane = tid & 63;
  const int st = w >> 1, qh = w & 1;
  const int l31 = lane & 31, hi = lane >> 5;

  const int LA = p + 1, LB = 64 - p;
  const int nA = (p >= 22) ? 2 : 1;

  int len[4], kb[4], tA[4];
  if (nA == 1) {
    len[0] = LA; kb[0] = 0; tA[0] = 1;
    int q3 = LB / 3, r3 = LB % 3;
    len[1] = q3 + (r3 > 0); len[2] = q3 + (r3 > 1); len[3] = q3;
    kb[1] = 0; kb[2] = len[1]; kb[3] = len[1] + len[2];
    tA[1] = tA[2] = tA[3] = 0;
  } else {
    len[0] = (LA + 1) >> 1; len[1] = LA - len[0];
    kb[0] = 0; kb[1] = len[0]; tA[0] = tA[1] = 1;
    len[2] = (LB + 1) >> 1; len[3] = LB - len[2];
    kb[2] = 0; kb[3] = len[2]; tA[2] = tA[3] = 0;
  }
  int wall = len[0];
#pragma unroll
  for (int i = 1; i < 4; i++) wall = len[i] > wall ? len[i] : wall;

  const int isA = tA[st];
  const int qt = isA ? p : pB;
  const int kbase = kb[st], mylen = len[st];

  bf16* const Kb = KVs[2 * st];
  bf16* const Vb = KVs[2 * st + 1];

  // Q fragments: direct global loads (once). row qt*64+qh*32+l31, col 16D+8hi
  short8 qf[4];
  {
    const bf16* qr = Qh + (size_t)(qt * 64 + qh * 32 + l31) * 64 + 8 * hi;
#pragma unroll
    for (int D = 0; D < 4; D++) qf[D] = *(const short8*)(qr + 16 * D);
  }

  // DMA staging geometry: 8 gload16 cover 64 rows x 128B; source chunk
  // pre-swizzled so LDS reads use lsw().
  const int srow = lane >> 3;
  const int scl = (lane & 7) ^ (srow & 7);

  auto stageK = [&](int kt) {
#pragma unroll
    for (int j = 0; j < 8; j++)
      gload16(&Kh[(size_t)(kt * 64 + 8 * j + srow) * 64 + scl * 8],
              &Kb[(8 * j) * 64]);
  };
  auto stageV = [&](int kt) {
#pragma unroll
    for (int j = 0; j < 8; j++)
      gload16(&Vth[(size_t)(8 * j + srow) * T + kt * 64 + scl * 8],
              &Vb[(8 * j) * 64]);
  };

  if (qh == 0) stageK(kbase); else stageV(kbase);
  __syncthreads();  // first tiles staged (DMA drained by barrier)

  f32x16 O0 = {}, O1 = {};
  float l_lane = 0.f;

  for (int s = 0; s < wall; s++) {
    if (s < mylen) {
      const int kt = kbase + s;
      const bool diag = (kt == qt);
#pragma unroll
      for (int H = 0; H < 2; H++) {
        f32x16 S = {};
        __builtin_amdgcn_s_setprio(1);
#pragma unroll
        for (int D = 0; D < 4; D++) {
          short8 kf = *(const short8*)&Kb[lsw(32 * H + l31, 16 * D + 8 * hi)];
          S = MFMA32(kf, qf[D], S);
        }
        __builtin_amdgcn_s_setprio(0);
        short8 p0, p1;
#pragma unroll
        for (int r = 0; r < 16; r++) {
          float pv = exp2f(S[r]);
          if (diag) {
            int kl = 32 * H + (r & 3) + 8 * (r >> 2) + 4 * hi;
            pv = (kl > qh * 32 + l31) ? 0.f : pv;
          }
          l_lane += pv;
          short bb = bfbits(pv);
          if (r < 8) p0[r] = bb;
          else       p1[r - 8] = bb;
        }
        __builtin_amdgcn_s_setprio(1);
#pragma unroll
        for (int j = 0; j < 2; j++) {
          short8 pj = j ? p1 : p0;
          short8 v0 = *(const short8*)&Vb[lsw(l31, 32 * H + 16 * j + 8 * hi)];
          short8 v1 = *(const short8*)&Vb[lsw(32 + l31, 32 * H + 16 * j + 8 * hi)];
          O0 = MFMA32(pj, v0, O0);
          O1 = MFMA32(pj, v1, O1);
        }
        __builtin_amdgcn_s_setprio(0);
      }
    }
    __syncthreads();  // all readers of this stream's bufs done
    if (s + 1 < mylen) {
      if (qh == 0) stageK(kbase + s + 1);
      else         stageV(kbase + s + 1);
    }
    __syncthreads();  // next tiles staged
  }

  // fold l across the hi halves (partner lane covers the other 32 k's)
  l_lane += __shfl_xor(l_lane, 32, 64);

  // dump partial O (+l) to this wave's 8KB region
  float* myR = (float*)&KVs[w][0];
#pragma unroll
  for (int r = 0; r < 16; r++) {
    int q = (r & 3) + 8 * (r >> 2) + 4 * hi;
    myR[q * 64 + l31] = O0[r];
    myR[q * 64 + 32 + l31] = O1[r];
  }
  if (lane < 32) Lsh[w][lane] = l_lane;
  __syncthreads();

  // owner (first stream of each tile) combines its task's partials
  const int first = isA ? 0 : nA;
  const int nSt = isA ? nA : (4 - nA);
  if (st == first) {
    const size_t yb0 = ((size_t)b * T + qt * 64 + qh * 32) * 512 + h * 64;
#pragma unroll 4
    for (int qi = 0; qi < 16; qi++) {
      const int q = 16 * hi + qi;
      float s0 = 0.f, s1 = 0.f, lt = 0.f;
      for (int i = 0; i < nSt; i++) {
        const int ws = (first + i) * 2 + qh;
        const float* R = (const float*)&KVs[ws][0];
        s0 += R[q * 64 + l31];
        s1 += R[q * 64 + 32 + l31];
        lt += Lsh[ws][q];
      }
      const float inv = 1.f / lt;
      Y[yb0 + (size_t)q * 512 + l31] = (bf16)(s0 * inv);
      Y[yb0 + (size_t)q * 512 + 32 + l31] = (bf16)(s1 * inv);
    }
  }
}

// ---------------------------------------------------------------------------
extern "C" void kernel_launch(void* const* d_in, const int* in_sizes, int n_in,
                              void* d_out, int out_size, void* d_ws, size_t ws_size,
                              hipStream_t stream) {
  (void)out_size; (void)ws_size;
  // Interface verified R9: dict-order slots, fp32 in, x=[B,T,C], fp32 out.
  const int NX = 8192 * 512;
  int xi = 0;
  for (int i = 0; i < n_in; i++)
    if (in_sizes[i] == NX) { xi = i; break; }
  const float* x = (const float*)d_in[xi];
  const float* wsrc[4];
  int wn = 0;
  for (int i = 0; i < n_in && wn < 4; i++)
    if (i != xi) wsrc[wn++] = (const float*)d_in[i];

  bf16* ws = (bf16*)d_ws;
  const size_t HE = (size_t)NX;
  bf16* q  = ws;                 // 8 MB
  bf16* k  = q + HE;             // 8 MB
  bf16* yx = k + HE;             // 8 MB: bf16 x during qkv, y after attn
  bf16* cw = yx + HE;            // 2 MB (4 weights)  -> 26 MB ws total
  bf16* vt = (bf16*)d_out;       // V^T staged in d_out, consumed before proj
  float* out = (float*)d_out;

  conv_all<<<2560, 256, 0, stream>>>(x, wsrc[0], wsrc[1], wsrc[2], wsrc[3],
                                     yx, cw);
  qkv_kernel<<<dim3(64, 4, 3), 256, 0, stream>>>(yx, cw, q, k, vt);
  attn_kernel<<<512, 512, 0, stream>>>(q, k, vt, yx);
  proj_kernel<<<dim3(128, 4), 256, 0, stream>>>(yx, cw + 3 * 262144, out);
}